// Round 10
// baseline (452.840 us; speedup 1.0000x reference)
//
#include <hip/hip_runtime.h>
#include <stdint.h>

// FeaturePlanes: N=1M points (INDIM=4), P=6 pairs, FDIM=16 channels, S=1025.
// out[n, p*16 + c] = bilinear(fm[p, c, :, :], x=x[n,ii[p]], y=x[n,jj[p]])
//
// R10: R9's quad layout + Y-BAND MULTIPASS sampling. Sample is MSHR/latency
// bound (R6 vs R9: FETCH 771->660 MB, dur 306->312 us — insensitive to bytes).
// Grid (nb, 8 bands, 6 pairs); a block only processes samples whose y0-band
// matches blockIdx.y -> in-flight plane footprint = 64 quad-rows = 2.1 MB,
// L2-resident per XCD, converting ~L3-latency reuse touches into L2 hits.
// x (16 MB) and q8 (101 MB) fit L3 -> the 8x x re-read costs no HBM traffic.
// Writes stay n-ordered, disjoint across bands -> deterministic.
// Precision: per-row-pair scale, quant err <= amax/254 ~ 2.2e-4; measured
// absmax 2.44e-4 vs threshold 1.0156e-3.

#define FP_S 1025
#define FP_C 16
#define FP_P 6
#define FP_Q 513  // quads per dim (ceil(1025/2))

typedef float f32x2 __attribute__((ext_vector_type(2)));
typedef float f32x4 __attribute__((ext_vector_type(4)));

__device__ __forceinline__ int fp_qsat(float v, float inv) {
    int q = (int)rintf(v * inv);
    return q > 127 ? 127 : (q < -127 ? -127 : q);
}

__device__ __forceinline__ uint32_t fp_q4(float a, float b, float c, float d, float inv) {
    return ((uint32_t)(fp_qsat(a, inv) & 0xff)) | ((uint32_t)(fp_qsat(b, inv) & 0xff) << 8) |
           ((uint32_t)(fp_qsat(c, inv) & 0xff) << 16) | ((uint32_t)(fp_qsat(d, inv) & 0xff) << 24);
}

__device__ __forceinline__ uint4 fp_pack16v(const f32x2* v, int comp, float inv) {
    uint4 r;
    r.x = fp_q4(v[0][comp], v[1][comp], v[2][comp], v[3][comp], inv);
    r.y = fp_q4(v[4][comp], v[5][comp], v[6][comp], v[7][comp], inv);
    r.z = fp_q4(v[8][comp], v[9][comp], v[10][comp], v[11][comp], inv);
    r.w = fp_q4(v[12][comp], v[13][comp], v[14][comp], v[15][comp], inv);
    return r;
}

__device__ __forceinline__ uint4 fp_pack16s(const float* v, float inv) {
    uint4 r;
    r.x = fp_q4(v[0], v[1], v[2], v[3], inv);
    r.y = fp_q4(v[4], v[5], v[6], v[7], inv);
    r.z = fp_q4(v[8], v[9], v[10], v[11], inv);
    r.w = fp_q4(v[12], v[13], v[14], v[15], inv);
    return r;
}

// ---- prep: fm[p][c][y][x] fp32 -> quad layout q8[p][Y][X][dy][dx][c] int8 + rs[p][Y] ----
__global__ __launch_bounds__(512) void fp_quadquant(const float* __restrict__ fm,
                                                    uint4* __restrict__ q8,
                                                    float* __restrict__ rs) {
    const size_t plane = (size_t)FP_S * FP_S;
    int Y = blockIdx.x;   // 0..512
    int p = blockIdx.z;
    int t = threadIdx.x;  // 0..511 -> quad X = t; t==0 also handles X=512
    int y0 = 2 * Y;
    bool hasy1 = (y0 + 1) < FP_S;  // false only for Y=512
    const float* pb = fm + (size_t)p * FP_C * plane;
    const float* r0 = pb + (size_t)y0 * FP_S;
    const float* r1 = hasy1 ? r0 + FP_S : r0;  // alias: dy1 slots of Y=512 are never sampled

    // one quad per thread: texels x=2t,2t+1 of rows y0,y1 (all 16 channels)
    f32x2 v0[FP_C], v1[FP_C];
    float m = 0.0f;
    int x = 2 * t;  // <= 1022, x+1 always valid
#pragma unroll
    for (int c = 0; c < FP_C; ++c) {
        v0[c] = *(const f32x2*)(r0 + (size_t)c * plane + x);
        v1[c] = *(const f32x2*)(r1 + (size_t)c * plane + x);
        m = fmaxf(m, fmaxf(fmaxf(fabsf(v0[c][0]), fabsf(v0[c][1])),
                           fmaxf(fabsf(v1[c][0]), fabsf(v1[c][1]))));
    }
    // tail column x=1024 contributes to amax (loaded again later, L1-hot)
    if (t == 0) {
#pragma unroll
        for (int c = 0; c < FP_C; ++c) {
            m = fmaxf(m, fabsf(r0[(size_t)c * plane + 1024]));
            m = fmaxf(m, fabsf(r1[(size_t)c * plane + 1024]));
        }
    }

    __shared__ float red[512];
    red[t] = m;
    __syncthreads();
#pragma unroll
    for (int s = 256; s > 0; s >>= 1) {
        if (t < s) red[t] = fmaxf(red[t], red[t + s]);
        __syncthreads();
    }
    float am = red[0];
    float inv = (am > 0.0f) ? 127.0f / am : 0.0f;
    if (t == 0) rs[p * FP_Q + Y] = am * (1.0f / 127.0f);

    // quantize from registers; 64 B contiguous store per quad
    uint4* qb_ = q8 + (((size_t)p * FP_Q + Y) * FP_Q + t) * 4;
    qb_[0] = fp_pack16v(v0, 0, inv);  // (dy0,dx0)
    qb_[1] = fp_pack16v(v0, 1, inv);  // (dy0,dx1)
    qb_[2] = fp_pack16v(v1, 0, inv);  // (dy1,dx0)
    qb_[3] = fp_pack16v(v1, 1, inv);  // (dy1,dx1)

    // tail quad X=512: only dx=0 slots are ever sampled (x<=1024)
    if (t == 0) {
        float c0[FP_C], c1[FP_C];
#pragma unroll
        for (int c = 0; c < FP_C; ++c) {
            c0[c] = r0[(size_t)c * plane + 1024];
            c1[c] = r1[(size_t)c * plane + 1024];
        }
        uint4* qt = q8 + (((size_t)p * FP_Q + Y) * FP_Q + 512) * 4;
        qt[0] = fp_pack16s(c0, inv);
        qt[1] = make_uint4(0, 0, 0, 0);
        qt[2] = fp_pack16s(c1, inv);
        qt[3] = make_uint4(0, 0, 0, 0);
    }
}

// signed byte b of word w -> float
__device__ __forceinline__ float fp_b8(uint32_t w, int b) {
    return (float)((int)(w << (24 - 8 * b)) >> 24);
}

__device__ __forceinline__ void fp_pair(int p, int& ii, int& jj) {
    // pairs: (0,1),(0,2),(0,3),(1,2),(1,3),(2,3) — p is wave-uniform (blockIdx.z)
    switch (p) {
        case 0: ii = 0; jj = 1; break;
        case 1: ii = 0; jj = 2; break;
        case 2: ii = 0; jj = 3; break;
        case 3: ii = 1; jj = 2; break;
        case 4: ii = 1; jj = 3; break;
        default: ii = 2; jj = 3; break;
    }
}

// ---- y-banded p-major sample from quad layout, 1 point/thread ----
__global__ __launch_bounds__(256) void fp_sample_qb(const float* __restrict__ xin,
                                                    const uint4* __restrict__ q8,
                                                    const float* __restrict__ rs,
                                                    float* __restrict__ out, int N) {
    int n = blockIdx.x * 256 + threadIdx.x;
    if (n >= N) return;
    int p = blockIdx.z;
    int ii, jj;
    fp_pair(p, ii, jj);

    float4 xr = ((const float4*)xin)[n];
    float xv = (ii == 0) ? xr.x : ((ii == 1) ? xr.y : xr.z);  // ii in {0,1,2}
    float yv = (jj == 1) ? xr.y : ((jj == 2) ? xr.z : xr.w);  // jj in {1,2,3}

    float px = fminf(fmaxf((xv + 1.0f) * 512.0f, 0.0f), 1024.0f);
    float py = fminf(fmaxf((yv + 1.0f) * 512.0f, 0.0f), 1024.0f);
    float fx0 = floorf(px), fy0 = floorf(py);
    int x0 = (int)fx0, y0 = (int)fy0;

    // band gate: this block only handles samples whose y0-band matches.
    // Band = 64 quad-rows = 2.1 MB of q8 -> L2-resident working set.
    int band = min(y0 >> 7, 7);
    if (band != (int)blockIdx.y) return;

    int x1 = min(x0 + 1, FP_S - 1);
    int y1 = min(y0 + 1, FP_S - 1);
    float wx = px - fx0, wy = py - fy0;

    const float* prs = rs + p * FP_Q;  // 2 KB/pair, L1-resident
    float s0 = prs[y0 >> 1], s1 = prs[y1 >> 1];
    float w00 = (1.0f - wx) * (1.0f - wy) * s0;
    float w01 = wx * (1.0f - wy) * s0;
    float w10 = (1.0f - wx) * wy * s1;
    float w11 = wx * wy * s1;

    const uint4* pq = q8 + (size_t)p * FP_Q * FP_Q * 4;
    // slot index of texel (y,x) in quad layout
    size_t ia = ((size_t)((y0 >> 1) * FP_Q + (x0 >> 1))) * 4 + ((y0 & 1) * 2 + (x0 & 1));
    size_t ib = ((size_t)((y0 >> 1) * FP_Q + (x1 >> 1))) * 4 + ((y0 & 1) * 2 + (x1 & 1));
    size_t ic = ((size_t)((y1 >> 1) * FP_Q + (x0 >> 1))) * 4 + ((y1 & 1) * 2 + (x0 & 1));
    size_t id = ((size_t)((y1 >> 1) * FP_Q + (x1 >> 1))) * 4 + ((y1 & 1) * 2 + (x1 & 1));
    uint4 qa = pq[ia];
    uint4 qb = pq[ib];
    uint4 qc = pq[ic];
    uint4 qd = pq[id];

    uint32_t wa[4] = {qa.x, qa.y, qa.z, qa.w};
    uint32_t wb[4] = {qb.x, qb.y, qb.z, qb.w};
    uint32_t wc[4] = {qc.x, qc.y, qc.z, qc.w};
    uint32_t wd[4] = {qd.x, qd.y, qd.z, qd.w};

    f32x4* o = (f32x4*)(out + (size_t)n * (FP_P * FP_C) + p * FP_C);
#pragma unroll
    for (int r = 0; r < 4; ++r) {
        f32x4 rr;
#pragma unroll
        for (int bb = 0; bb < 4; ++bb) {
            rr[bb] = w00 * fp_b8(wa[r], bb) + w01 * fp_b8(wb[r], bb) +
                     w10 * fp_b8(wc[r], bb) + w11 * fp_b8(wd[r], bb);
        }
        o[r] = rr;
    }
}

// ---------------- fallback: sample directly from channel-major fp32 fm ----------------
__global__ __launch_bounds__(256) void fp_sample_direct(const float* __restrict__ xin,
                                                        const float* __restrict__ fm,
                                                        float* __restrict__ out, int N) {
    int n = blockIdx.x * 256 + threadIdx.x;
    if (n >= N) return;
    int p = blockIdx.z;
    int ii, jj;
    fp_pair(p, ii, jj);

    float4 xr = ((const float4*)xin)[n];
    float xv = (ii == 0) ? xr.x : ((ii == 1) ? xr.y : xr.z);
    float yv = (jj == 1) ? xr.y : ((jj == 2) ? xr.z : xr.w);

    float px = fminf(fmaxf((xv + 1.0f) * 512.0f, 0.0f), 1024.0f);
    float py = fminf(fmaxf((yv + 1.0f) * 512.0f, 0.0f), 1024.0f);
    float fx0 = floorf(px), fy0 = floorf(py);
    int x0 = (int)fx0, y0 = (int)fy0;
    int x1 = min(x0 + 1, FP_S - 1);
    int y1 = min(y0 + 1, FP_S - 1);
    float wx = px - fx0, wy = py - fy0;
    float w00 = (1.0f - wx) * (1.0f - wy), w01 = wx * (1.0f - wy);
    float w10 = (1.0f - wx) * wy, w11 = wx * wy;

    const size_t plane = (size_t)FP_S * FP_S;
    const float* pl = fm + (size_t)p * FP_C * plane;
    float res[FP_C];
#pragma unroll
    for (int c = 0; c < FP_C; ++c) {
        const float* plc = pl + (size_t)c * plane;
        float a = plc[(size_t)y0 * FP_S + x0];
        float bq = plc[(size_t)y0 * FP_S + x1];
        float g = plc[(size_t)y1 * FP_S + x0];
        float d = plc[(size_t)y1 * FP_S + x1];
        res[c] = a * w00 + bq * w01 + g * w10 + d * w11;
    }
    f32x4* o = (f32x4*)(out + (size_t)n * (FP_P * FP_C) + p * FP_C);
#pragma unroll
    for (int k = 0; k < 4; ++k) {
        f32x4 r = {res[4 * k], res[4 * k + 1], res[4 * k + 2], res[4 * k + 3]};
        o[k] = r;
    }
}

static inline size_t fp_align(size_t v) { return (v + 255) & ~(size_t)255; }

extern "C" void kernel_launch(void* const* d_in, const int* in_sizes, int n_in,
                              void* d_out, int out_size, void* d_ws, size_t ws_size,
                              hipStream_t stream) {
    const float* x = (const float*)d_in[0];
    const float* fm = (const float*)d_in[1];
    float* out = (float*)d_out;
    int N = in_sizes[0] / 4;

    size_t q8_bytes = (size_t)FP_P * FP_Q * FP_Q * 64;  // ~101.1 MB
    size_t rs_off = fp_align(q8_bytes);
    size_t needed = rs_off + (size_t)FP_P * FP_Q * sizeof(float);  // +12.3 KB

    if (ws_size >= needed) {
        uint4* q8 = (uint4*)d_ws;
        float* rs = (float*)((char*)d_ws + rs_off);

        dim3 gQ(FP_Q, 1, FP_P);
        fp_quadquant<<<gQ, 512, 0, stream>>>(fm, q8, rs);

        dim3 gS((unsigned)((N + 255) / 256), 8, FP_P);
        fp_sample_qb<<<gS, 256, 0, stream>>>(x, q8, rs, out, N);
    } else {
        dim3 gS((unsigned)((N + 255) / 256), 1, FP_P);
        fp_sample_direct<<<gS, 256, 0, stream>>>(x, fm, out, N);
    }
}

// Round 11
// 430.327 us; speedup vs baseline: 1.0523x; 1.0523x over previous
//
#include <hip/hip_runtime.h>
#include <stdint.h>

// FeaturePlanes: N=1M points (INDIM=4), P=6 pairs, FDIM=16 channels, S=1025.
// out[n, p*16 + c] = bilinear(fm[p, c, :, :], x=x[n,ii[p]], y=x[n,jj[p]])
//
// R11: sample = R9's quad-layout p-major gather (1 pt/thread) — measured at
// the request-rate floor (dur invariant ~306-355 us across FETCH 135-771 MB;
// R3 sorted, R9 unsorted, R10 banded all converge). Prep widened to 16 B
// loads: thread handles 2 adjacent quads (texels x=4t..4t+3, rows y0,y1),
// 128 B contiguous store. fm read from HBM exactly once.
// Precision: per-row-pair scale, quant err <= amax/254 ~ 2.2e-4; measured
// absmax 2.44e-4 vs threshold 1.0156e-3.

#define FP_S 1025
#define FP_C 16
#define FP_P 6
#define FP_Q 513  // quads per dim (ceil(1025/2))

typedef float f32x4 __attribute__((ext_vector_type(4)));

__device__ __forceinline__ int fp_qsat(float v, float inv) {
    int q = (int)rintf(v * inv);
    return q > 127 ? 127 : (q < -127 ? -127 : q);
}

__device__ __forceinline__ uint32_t fp_q4(float a, float b, float c, float d, float inv) {
    return ((uint32_t)(fp_qsat(a, inv) & 0xff)) | ((uint32_t)(fp_qsat(b, inv) & 0xff) << 8) |
           ((uint32_t)(fp_qsat(c, inv) & 0xff) << 16) | ((uint32_t)(fp_qsat(d, inv) & 0xff) << 24);
}

// pack channel-component `comp` (0..3) of 16 f32x4 regs into one uint4 (16 ch x int8)
__device__ __forceinline__ uint4 fp_pack16v(const f32x4* v, int comp, float inv) {
    uint4 r;
    r.x = fp_q4(v[0][comp], v[1][comp], v[2][comp], v[3][comp], inv);
    r.y = fp_q4(v[4][comp], v[5][comp], v[6][comp], v[7][comp], inv);
    r.z = fp_q4(v[8][comp], v[9][comp], v[10][comp], v[11][comp], inv);
    r.w = fp_q4(v[12][comp], v[13][comp], v[14][comp], v[15][comp], inv);
    return r;
}

__device__ __forceinline__ uint4 fp_pack16s(const float* v, float inv) {
    uint4 r;
    r.x = fp_q4(v[0], v[1], v[2], v[3], inv);
    r.y = fp_q4(v[4], v[5], v[6], v[7], inv);
    r.z = fp_q4(v[8], v[9], v[10], v[11], inv);
    r.w = fp_q4(v[12], v[13], v[14], v[15], inv);
    return r;
}

// ---- prep: fm[p][c][y][x] fp32 -> quad layout q8[p][Y][X][dy][dx][c] int8 + rs[p][Y] ----
// block = one (p,Y) row-pair; 256 threads; thread t handles quads X=2t, 2t+1
// (texels x=4t..4t+3 of rows y0,y1) via 16 B loads; 128 B contiguous store.
__global__ __launch_bounds__(256) void fp_quadquant4(const float* __restrict__ fm,
                                                     uint4* __restrict__ q8,
                                                     float* __restrict__ rs) {
    const size_t plane = (size_t)FP_S * FP_S;
    int Y = blockIdx.x;   // 0..512
    int p = blockIdx.z;
    int t = threadIdx.x;  // 0..255
    int y0 = 2 * Y;
    bool hasy1 = (y0 + 1) < FP_S;  // false only for Y=512
    const float* pb = fm + (size_t)p * FP_C * plane;
    const float* r0 = pb + (size_t)y0 * FP_S;
    const float* r1 = hasy1 ? r0 + FP_S : r0;  // alias: dy1 slots of Y=512 never sampled

    int x = 4 * t;  // 0..1020; x..x+3 valid (<=1023)
    f32x4 v0[FP_C], v1[FP_C];
    float m = 0.0f;
#pragma unroll
    for (int c = 0; c < FP_C; ++c) {
        v0[c] = *(const f32x4*)(r0 + (size_t)c * plane + x);
        v1[c] = *(const f32x4*)(r1 + (size_t)c * plane + x);
        m = fmaxf(m, fmaxf(fmaxf(fabsf(v0[c][0]), fabsf(v0[c][1])),
                           fmaxf(fabsf(v0[c][2]), fabsf(v0[c][3]))));
        m = fmaxf(m, fmaxf(fmaxf(fabsf(v1[c][0]), fabsf(v1[c][1])),
                           fmaxf(fabsf(v1[c][2]), fabsf(v1[c][3]))));
    }
    // tail column x=1024 contributes to amax (re-loaded L1-hot for the store below)
    if (t == 0) {
#pragma unroll
        for (int c = 0; c < FP_C; ++c) {
            m = fmaxf(m, fabsf(r0[(size_t)c * plane + 1024]));
            m = fmaxf(m, fabsf(r1[(size_t)c * plane + 1024]));
        }
    }

    __shared__ float red[256];
    red[t] = m;
    __syncthreads();
#pragma unroll
    for (int s = 128; s > 0; s >>= 1) {
        if (t < s) red[t] = fmaxf(red[t], red[t + s]);
        __syncthreads();
    }
    float am = red[0];
    float inv = (am > 0.0f) ? 127.0f / am : 0.0f;
    if (t == 0) rs[p * FP_Q + Y] = am * (1.0f / 127.0f);

    // two quads, 8 consecutive uint4 = 128 B contiguous per thread
    uint4* qb_ = q8 + (((size_t)p * FP_Q + Y) * FP_Q + 2 * t) * 4;
    qb_[0] = fp_pack16v(v0, 0, inv);  // quad X=2t   (dy0,dx0)
    qb_[1] = fp_pack16v(v0, 1, inv);  //             (dy0,dx1)
    qb_[2] = fp_pack16v(v1, 0, inv);  //             (dy1,dx0)
    qb_[3] = fp_pack16v(v1, 1, inv);  //             (dy1,dx1)
    qb_[4] = fp_pack16v(v0, 2, inv);  // quad X=2t+1 (dy0,dx0)
    qb_[5] = fp_pack16v(v0, 3, inv);  //             (dy0,dx1)
    qb_[6] = fp_pack16v(v1, 2, inv);  //             (dy1,dx0)
    qb_[7] = fp_pack16v(v1, 3, inv);  //             (dy1,dx1)

    // tail quad X=512: only dx=0 slots are ever sampled (x<=1024)
    if (t == 0) {
        float c0[FP_C], c1[FP_C];
#pragma unroll
        for (int c = 0; c < FP_C; ++c) {
            c0[c] = r0[(size_t)c * plane + 1024];
            c1[c] = r1[(size_t)c * plane + 1024];
        }
        uint4* qt = q8 + (((size_t)p * FP_Q + Y) * FP_Q + 512) * 4;
        qt[0] = fp_pack16s(c0, inv);
        qt[1] = make_uint4(0, 0, 0, 0);
        qt[2] = fp_pack16s(c1, inv);
        qt[3] = make_uint4(0, 0, 0, 0);
    }
}

// signed byte b of word w -> float
__device__ __forceinline__ float fp_b8(uint32_t w, int b) {
    return (float)((int)(w << (24 - 8 * b)) >> 24);
}

__device__ __forceinline__ void fp_pair(int p, int& ii, int& jj) {
    // pairs: (0,1),(0,2),(0,3),(1,2),(1,3),(2,3) — p is wave-uniform (blockIdx.z)
    switch (p) {
        case 0: ii = 0; jj = 1; break;
        case 1: ii = 0; jj = 2; break;
        case 2: ii = 0; jj = 3; break;
        case 3: ii = 1; jj = 2; break;
        case 4: ii = 1; jj = 3; break;
        default: ii = 2; jj = 3; break;
    }
}

// ---- p-major sample from quad layout, 1 point/thread (R9 config, unchanged) ----
__global__ __launch_bounds__(256) void fp_sample_qq(const float* __restrict__ xin,
                                                    const uint4* __restrict__ q8,
                                                    const float* __restrict__ rs,
                                                    float* __restrict__ out, int N) {
    int n = blockIdx.x * 256 + threadIdx.x;
    if (n >= N) return;
    int p = blockIdx.z;
    int ii, jj;
    fp_pair(p, ii, jj);

    float4 xr = ((const float4*)xin)[n];
    float xv = (ii == 0) ? xr.x : ((ii == 1) ? xr.y : xr.z);  // ii in {0,1,2}
    float yv = (jj == 1) ? xr.y : ((jj == 2) ? xr.z : xr.w);  // jj in {1,2,3}

    float px = fminf(fmaxf((xv + 1.0f) * 512.0f, 0.0f), 1024.0f);
    float py = fminf(fmaxf((yv + 1.0f) * 512.0f, 0.0f), 1024.0f);
    float fx0 = floorf(px), fy0 = floorf(py);
    int x0 = (int)fx0, y0 = (int)fy0;
    int x1 = min(x0 + 1, FP_S - 1);
    int y1 = min(y0 + 1, FP_S - 1);
    float wx = px - fx0, wy = py - fy0;

    const float* prs = rs + p * FP_Q;  // 2 KB/pair, L1-resident
    float s0 = prs[y0 >> 1], s1 = prs[y1 >> 1];
    float w00 = (1.0f - wx) * (1.0f - wy) * s0;
    float w01 = wx * (1.0f - wy) * s0;
    float w10 = (1.0f - wx) * wy * s1;
    float w11 = wx * wy * s1;

    const uint4* pq = q8 + (size_t)p * FP_Q * FP_Q * 4;
    // slot index of texel (y,x) in quad layout
    size_t ia = ((size_t)((y0 >> 1) * FP_Q + (x0 >> 1))) * 4 + ((y0 & 1) * 2 + (x0 & 1));
    size_t ib = ((size_t)((y0 >> 1) * FP_Q + (x1 >> 1))) * 4 + ((y0 & 1) * 2 + (x1 & 1));
    size_t ic = ((size_t)((y1 >> 1) * FP_Q + (x0 >> 1))) * 4 + ((y1 & 1) * 2 + (x0 & 1));
    size_t id = ((size_t)((y1 >> 1) * FP_Q + (x1 >> 1))) * 4 + ((y1 & 1) * 2 + (x1 & 1));
    uint4 qa = pq[ia];
    uint4 qb = pq[ib];
    uint4 qc = pq[ic];
    uint4 qd = pq[id];

    uint32_t wa[4] = {qa.x, qa.y, qa.z, qa.w};
    uint32_t wb[4] = {qb.x, qb.y, qb.z, qb.w};
    uint32_t wc[4] = {qc.x, qc.y, qc.z, qc.w};
    uint32_t wd[4] = {qd.x, qd.y, qd.z, qd.w};

    f32x4* o = (f32x4*)(out + (size_t)n * (FP_P * FP_C) + p * FP_C);
#pragma unroll
    for (int r = 0; r < 4; ++r) {
        f32x4 rr;
#pragma unroll
        for (int bb = 0; bb < 4; ++bb) {
            rr[bb] = w00 * fp_b8(wa[r], bb) + w01 * fp_b8(wb[r], bb) +
                     w10 * fp_b8(wc[r], bb) + w11 * fp_b8(wd[r], bb);
        }
        o[r] = rr;
    }
}

// ---------------- fallback: sample directly from channel-major fp32 fm ----------------
__global__ __launch_bounds__(256) void fp_sample_direct(const float* __restrict__ xin,
                                                        const float* __restrict__ fm,
                                                        float* __restrict__ out, int N) {
    int n = blockIdx.x * 256 + threadIdx.x;
    if (n >= N) return;
    int p = blockIdx.z;
    int ii, jj;
    fp_pair(p, ii, jj);

    float4 xr = ((const float4*)xin)[n];
    float xv = (ii == 0) ? xr.x : ((ii == 1) ? xr.y : xr.z);
    float yv = (jj == 1) ? xr.y : ((jj == 2) ? xr.z : xr.w);

    float px = fminf(fmaxf((xv + 1.0f) * 512.0f, 0.0f), 1024.0f);
    float py = fminf(fmaxf((yv + 1.0f) * 512.0f, 0.0f), 1024.0f);
    float fx0 = floorf(px), fy0 = floorf(py);
    int x0 = (int)fx0, y0 = (int)fy0;
    int x1 = min(x0 + 1, FP_S - 1);
    int y1 = min(y0 + 1, FP_S - 1);
    float wx = px - fx0, wy = py - fy0;
    float w00 = (1.0f - wx) * (1.0f - wy), w01 = wx * (1.0f - wy);
    float w10 = (1.0f - wx) * wy, w11 = wx * wy;

    const size_t plane = (size_t)FP_S * FP_S;
    const float* pl = fm + (size_t)p * FP_C * plane;
    float res[FP_C];
#pragma unroll
    for (int c = 0; c < FP_C; ++c) {
        const float* plc = pl + (size_t)c * plane;
        float a = plc[(size_t)y0 * FP_S + x0];
        float bq = plc[(size_t)y0 * FP_S + x1];
        float g = plc[(size_t)y1 * FP_S + x0];
        float d = plc[(size_t)y1 * FP_S + x1];
        res[c] = a * w00 + bq * w01 + g * w10 + d * w11;
    }
    f32x4* o = (f32x4*)(out + (size_t)n * (FP_P * FP_C) + p * FP_C);
#pragma unroll
    for (int k = 0; k < 4; ++k) {
        f32x4 r = {res[4 * k], res[4 * k + 1], res[4 * k + 2], res[4 * k + 3]};
        o[k] = r;
    }
}

static inline size_t fp_align(size_t v) { return (v + 255) & ~(size_t)255; }

extern "C" void kernel_launch(void* const* d_in, const int* in_sizes, int n_in,
                              void* d_out, int out_size, void* d_ws, size_t ws_size,
                              hipStream_t stream) {
    const float* x = (const float*)d_in[0];
    const float* fm = (const float*)d_in[1];
    float* out = (float*)d_out;
    int N = in_sizes[0] / 4;

    size_t q8_bytes = (size_t)FP_P * FP_Q * FP_Q * 64;  // ~101.1 MB
    size_t rs_off = fp_align(q8_bytes);
    size_t needed = rs_off + (size_t)FP_P * FP_Q * sizeof(float);  // +12.3 KB

    if (ws_size >= needed) {
        uint4* q8 = (uint4*)d_ws;
        float* rs = (float*)((char*)d_ws + rs_off);

        dim3 gQ(FP_Q, 1, FP_P);
        fp_quadquant4<<<gQ, 256, 0, stream>>>(fm, q8, rs);

        dim3 gS((unsigned)((N + 255) / 256), 1, FP_P);
        fp_sample_qq<<<gS, 256, 0, stream>>>(x, q8, rs, out, N);
    } else {
        dim3 gS((unsigned)((N + 255) / 256), 1, FP_P);
        fp_sample_direct<<<gS, 256, 0, stream>>>(x, fm, out, N);
    }
}